// Round 9
// baseline (222.327 us; speedup 1.0000x reference)
//
#include <hip/hip_runtime.h>
#include <math.h>

#ifndef M_PI
#define M_PI 3.14159265358979323846
#endif

// Problem constants (setup_inputs: audio (32,2,441000) f32, scalar int params)
#define T_LEN      441000
#define L          16                          // samples per lane
#define WARM_LN    16                          // warm lanes per tile (256 samples)
#define OUT_W      ((64 - WARM_LN) * L)        // 768 stored samples per tile
#define WPC        ((T_LEN + OUT_W - 1) / OUT_W)   // 575 tiles per channel
#define BLOCK      256                         // 4 independent waves; no barriers, no LDS
#define NBLK       1024                        // persistent-ish grid: 4096 waves, ~9 tiles/wave

// d_ws layout (floats):
//   [0..4]            b0,b1,b2,a1,a2
//   [5+4j .. 8+4j]    M^(16*2^j) row-major, j=0..5          (scan levels)
//   [29+2k, 30+2k]    first row of M^(k+1), k=0..15         (output correction)

__device__ __forceinline__ double log_scale(double v, double mn, double mx) {
    v = fmin(fmax(v, mn), mx);
    double lmin = log(fmax(mn, 1e-6));
    double lmax = log(mx);
    double nrm = (log(fmax(v, 1e-6)) - lmin) / (lmax - lmin);
    return nrm * (mx - mn) + mn;
}

__global__ void eq_setup_kernel(const int* __restrict__ f_in,
                                const int* __restrict__ g_in,
                                const int* __restrict__ q_in,
                                float* __restrict__ ws) {
    // Single thread; all double math to match the numpy coefficient path.
    double f = log_scale((double)f_in[0], 20.0, 20000.0);
    double g = fmin(fmax((double)g_in[0], -30.0), 30.0);
    double Q = log_scale((double)q_in[0], 0.1, 30.0);
    double w0 = 2.0 * M_PI * f / 44100.0;
    double A  = pow(10.0, g / 40.0);
    double al = sin(w0) / (2.0 * Q);
    double ca = cos(w0);
    double b0 = 1.0 + al * A;
    double b1 = -2.0 * ca;
    double b2 = 1.0 - al * A;
    double a0 = 1.0 + al / A;
    double B0 = b0 / a0, B1 = b1 / a0, B2 = b2 / a0;
    double A1 = b1 / a0, A2 = (1.0 - al / A) / a0;
    ws[0] = (float)B0; ws[1] = (float)B1; ws[2] = (float)B2;
    ws[3] = (float)A1; ws[4] = (float)A2;

    // M = [[-a1, -a2], [1, 0]] acting on (y_n, y_{n-1}).
    const double m11 = -A1, m12 = -A2;

    // Scan matrices: M^16 .. M^512 by repeated squaring (double).
    double p11 = m11, p12 = m12, p21 = 1.0, p22 = 0.0;
    for (int i = 0; i < 4; ++i) {            // -> M^16
        double s11 = p11 * p11 + p12 * p21;
        double s12 = p11 * p12 + p12 * p22;
        double s21 = p21 * p11 + p22 * p21;
        double s22 = p21 * p12 + p22 * p22;
        p11 = s11; p12 = s12; p21 = s21; p22 = s22;
    }
    for (int j = 0; j < 6; ++j) {            // store M^(16*2^j), j=0..5
        ws[5 + 4 * j + 0] = (float)p11;
        ws[5 + 4 * j + 1] = (float)p12;
        ws[5 + 4 * j + 2] = (float)p21;
        ws[5 + 4 * j + 3] = (float)p22;
        double s11 = p11 * p11 + p12 * p21;
        double s12 = p11 * p12 + p12 * p22;
        double s21 = p21 * p11 + p22 * p21;
        double s22 = p21 * p12 + p22 * p22;
        p11 = s11; p12 = s12; p21 = s21; p22 = s22;
    }

    // Correction rows: first row of M^(k+1), k=0..15.
    // y_exact[k] = y_local[k] + (M^(k+1))_11 * s0 + (M^(k+1))_12 * s1,
    // where s = (y_-1, y_-2) is the lane's incoming state.
    double q11 = m11, q12 = m12, q21 = 1.0, q22 = 0.0;   // = M^1
    for (int k = 0; k < L; ++k) {
        ws[29 + 2 * k] = (float)q11;
        ws[30 + 2 * k] = (float)q12;
        const double n11 = m11 * q11 + m12 * q21;
        const double n12 = m11 * q12 + m12 * q22;
        q21 = q11; q22 = q12;
        q11 = n11; q12 = n12;
    }
}

// Issue the 5 float4 loads for tile index c (tile = channel c/WPC, position c%WPC).
__device__ __forceinline__ void load_chain(const float* __restrict__ x, int c, int lane,
                                           float4& vm, float4& v0, float4& v1,
                                           float4& v2, float4& v3) {
    const int ch   = c / WPC;                  // wave-uniform
    const int pos  = c - ch * WPC;
    const int base = pos * OUT_W - WARM_LN * L + lane * L;   // mult of 16, can be <0
    const float* __restrict__ xc = x + (size_t)ch * T_LEN;
    if (base >= 4 && base + L <= T_LEN) {
        vm = *reinterpret_cast<const float4*>(xc + base - 4);
        v0 = *reinterpret_cast<const float4*>(xc + base + 0);
        v1 = *reinterpret_cast<const float4*>(xc + base + 4);
        v2 = *reinterpret_cast<const float4*>(xc + base + 8);
        v3 = *reinterpret_cast<const float4*>(xc + base + 12);
    } else {
        float e[20];
#pragma unroll
        for (int k = 0; k < 20; ++k) {
            const int idx = base - 4 + k;
            e[k] = (idx >= 0 && idx < T_LEN) ? xc[idx] : 0.f;
        }
        vm = make_float4(e[0],  e[1],  e[2],  e[3]);
        v0 = make_float4(e[4],  e[5],  e[6],  e[7]);
        v1 = make_float4(e[8],  e[9],  e[10], e[11]);
        v2 = make_float4(e[12], e[13], e[14], e[15]);
        v3 = make_float4(e[16], e[17], e[18], e[19]);
    }
}

// One tile: fused local pass -> scan -> exclusive shift -> linear correction + store.
// (r4's exact arithmetic: zero initial state, 256-sample warm-up, absmax-verified.)
__device__ __forceinline__ void tile_pass(const float* __restrict__ ws, int lane, int c,
        float4 vm, float4 v0, float4 v1, float4 v2, float4 v3,
        float* __restrict__ y) {
    const int ch   = c / WPC;
    const int pos  = c - ch * WPC;
    const int base = pos * OUT_W - WARM_LN * L + lane * L;
    float* __restrict__ yc = y + (size_t)ch * T_LEN;

    const float b0 = ws[0], b1 = ws[1], b2 = ws[2], a1 = ws[3], a2 = ws[4];

    float xv[L];
    xv[0]=v0.x;  xv[1]=v0.y;  xv[2]=v0.z;  xv[3]=v0.w;
    xv[4]=v1.x;  xv[5]=v1.y;  xv[6]=v1.z;  xv[7]=v1.w;
    xv[8]=v2.x;  xv[9]=v2.y;  xv[10]=v2.z; xv[11]=v2.w;
    xv[12]=v3.x; xv[13]=v3.y; xv[14]=v3.z; xv[15]=v3.w;
    const float xm2 = vm.z, xm1 = vm.w;

    // Fused local pass: FIR + zero-state IIR; record local outputs yl[k].
    float yl[L];
    float c0 = 0.f, c1 = 0.f;                  // (y_n, y_{n-1}) zero-state
    {
        float xk1 = xm1, xk2 = xm2;
#pragma unroll
        for (int k = 0; k < L; ++k) {
            const float xk = xv[k];
            const float t  = fmaf(b0, xk, fmaf(b1, xk1, b2 * xk2));
            const float yn = fmaf(-a1, c0, fmaf(-a2, c1, t));
            c1 = c0; c0 = yn;
            xk2 = xk1; xk1 = xk;
            yl[k] = yn;
        }
    }

    // Inclusive affine wave scan; level j composes with A = M^(16*2^j).
#pragma unroll
    for (int j = 0; j < 6; ++j) {
        const float m11 = ws[5 + 4 * j + 0], m12 = ws[5 + 4 * j + 1];
        const float m21 = ws[5 + 4 * j + 2], m22 = ws[5 + 4 * j + 3];
        const float d0 = __shfl_up(c0, 1u << j);
        const float d1 = __shfl_up(c1, 1u << j);
        if (lane >= (1 << j)) {
            c0 = fmaf(m11, d0, fmaf(m12, d1, c0));
            c1 = fmaf(m21, d0, fmaf(m22, d1, c1));
        }
    }

    // Exclusive shift: s = exact incoming state (y_-1, y_-2) for this lane.
    float s0 = __shfl_up(c0, 1);
    float s1 = __shfl_up(c1, 1);
    if (lane == 0) { s0 = 0.f; s1 = 0.f; }

    // Linear output correction (2 FMAs/sample, fully parallel) + stores.
    if (lane >= WARM_LN && base < T_LEN) {
        if (base + L <= T_LEN) {
#pragma unroll
            for (int q = 0; q < L / 4; ++q) {
                float o[4];
#pragma unroll
                for (int r = 0; r < 4; ++r) {
                    const int k = 4 * q + r;
                    o[r] = fmaf(ws[29 + 2 * k], s0, fmaf(ws[30 + 2 * k], s1, yl[k]));
                }
                *reinterpret_cast<float4*>(yc + base + 4 * q) =
                    make_float4(o[0], o[1], o[2], o[3]);
            }
        } else {
#pragma unroll
            for (int k = 0; k < L; ++k)
                if (base + k < T_LEN)
                    yc[base + k] = fmaf(ws[29 + 2 * k], s0, fmaf(ws[30 + 2 * k], s1, yl[k]));
        }
    }
}

// Persistent waves, grid-stride over tiles, rotated 1-deep software pipeline:
// the NEXT tile's 5 loads are issued above a sched_barrier(0) (scheduler cannot
// sink them into the compute below), and their first use is the NEXT loop
// iteration's compute — so the compiler's own vmcnt wait lands one full
// compute-phase downstream. Every wave keeps ~5KB of loads in flight
// continuously instead of burst-then-silent (r0..r8's shared pathology).
__global__ __launch_bounds__(BLOCK, 4) void eq_main_kernel(
        const float* __restrict__ x,
        const float* __restrict__ ws,
        float* __restrict__ y,
        int ntot) {
    const int lane    = threadIdx.x & 63;
    const int wid     = blockIdx.x * (BLOCK / 64) + (threadIdx.x >> 6);
    const int wstride = gridDim.x * (BLOCK / 64);

    int c = wid;
    if (c >= ntot) return;                     // wave-uniform

    float4 Am, A0, A1, A2, A3, Bm, B0, B1, B2, B3;
    load_chain(x, c, lane, Am, A0, A1, A2, A3);

    for (;;) {
        // --- half 1: prefetch into B, compute A ---
        const int cn = c + wstride;
        const bool hn = (cn < ntot);           // wave-uniform
        if (hn) load_chain(x, cn, lane, Bm, B0, B1, B2, B3);
        __builtin_amdgcn_sched_barrier(0);     // B-loads pinned above A-compute
        tile_pass(ws, lane, c, Am, A0, A1, A2, A3, y);
        if (!hn) break;
        c = cn;

        // --- half 2: prefetch into A, compute B ---
        const int cn2 = c + wstride;
        const bool hn2 = (cn2 < ntot);
        if (hn2) load_chain(x, cn2, lane, Am, A0, A1, A2, A3);
        __builtin_amdgcn_sched_barrier(0);     // A-loads pinned above B-compute
        tile_pass(ws, lane, c, Bm, B0, B1, B2, B3, y);
        if (!hn2) break;
        c = cn2;
    }
}

extern "C" void kernel_launch(void* const* d_in, const int* in_sizes, int n_in,
                              void* d_out, int out_size, void* d_ws, size_t ws_size,
                              hipStream_t stream) {
    const float* x = (const float*)d_in[0];
    const int*   f = (const int*)d_in[1];
    const int*   g = (const int*)d_in[2];
    const int*   q = (const int*)d_in[3];
    float*       y  = (float*)d_out;
    float*       ws = (float*)d_ws;

    eq_setup_kernel<<<1, 1, 0, stream>>>(f, g, q, ws);

    const int nch  = in_sizes[0] / T_LEN;   // 64 for this problem
    const int ntot = nch * WPC;             // 36800 tiles
    eq_main_kernel<<<dim3(NBLK), dim3(BLOCK), 0, stream>>>(x, ws, y, ntot);
}